// Round 6
// baseline (272.298 us; speedup 1.0000x reference)
//
#include <hip/hip_runtime.h>

// DAS beamforming: out[b,z,x,k] = sum_c lerp(rf[b,c], delay(b,c,z,x))[k]
// Round 6: fp16-in-LDS with IN-KERNEL conversion (never read ws: R3 showed
// ws-resident data is poison-cold; R3 also validated fp16 numerics).
//  - gathers: 16 B/pair fp16 (was 32 B fp32) -> LDS traffic & bank-conflict
//    cycles halve (R5 analysis: conflicts were +67% on 32 B random gathers)
//  - 2 channels per phase, 8 phases: 32 KiB fp16 buffer x2 dbuf = 64 KiB/block,
//    2 blocks/CU (128 KiB LDS), half the barriers
//  - register prefetch inside the phase: global loads for phase p+1 issue
//    before compute of p, cvt+ds_write after -> L2 latency hidden under
//    compute, and the barrier's vmcnt(0) drain is free (loads already consumed)
//  - epilogue: disjoint partial stores to ws + reduce kernel (R4: contended
//    atomics ping-pong across XCDs, 276 MB write storm)

#define NBATCH 2
#define NC 128
#define NS 2048
#define NK 4
#define NM 65536                              // Nz*Nx pixels per batch

#define THREADS 1024
#define PX_PER_THREAD 2
#define PX_PER_BLOCK (THREADS * PX_PER_THREAD)   // 2048
#define C_PER_BLOCK 16
#define N_CHUNKS (NC / C_PER_BLOCK)           // 8
#define N_TILES (NM / PX_PER_BLOCK)           // 32
#define NBLOCKS (NBATCH * N_TILES * N_CHUNKS) // 512 = 2 blocks/CU, 32 waves/CU

#define CH_PER_PHASE 2
#define N_PHASES (C_PER_BLOCK / CH_PER_PHASE) // 8
#define SLAB_F4 (CH_PER_PHASE * NS * NK / 4)  // 4096 float4 = 64 KiB fp32/slab
#define SLAB_H  (CH_PER_PHASE * NS * NK)      // 16384 halves = 32 KiB fp16/slab
#define CH_H    (NS * NK)                     // 8192 halves per channel

#define PART_BYTES ((size_t)N_CHUNKS * NBATCH * NM * NK * 4)  // 16.8 MB

typedef __attribute__((ext_vector_type(4))) _Float16 half4;
typedef __attribute__((ext_vector_type(8))) _Float16 half8;

// Load this thread's 2 float4-pairs of a 64 KiB slab into registers.
__device__ __forceinline__ void load_slab(const float* slab, float4* f, int t) {
    const float4* src = (const float4*)slab;
    f[0] = src[2 * t];
    f[1] = src[2 * t + 1];
    f[2] = src[2 * (t + 1024)];
    f[3] = src[2 * (t + 1024) + 1];
}

// cvt fp32->fp16 and write as two 16-B lane-sequential LDS stores.
__device__ __forceinline__ void write_slab(const float4* f, _Float16* buf, int t) {
#pragma unroll
    for (int r = 0; r < 2; ++r) {
        const int q = r * 1024 + t;
        const float4 a = f[2 * r], b = f[2 * r + 1];
        half8 h;
        h[0] = (_Float16)a.x; h[1] = (_Float16)a.y;
        h[2] = (_Float16)a.z; h[3] = (_Float16)a.w;
        h[4] = (_Float16)b.x; h[5] = (_Float16)b.y;
        h[6] = (_Float16)b.z; h[7] = (_Float16)b.w;
        *(half8*)(buf + (size_t)q * 8) = h;   // 16 B aligned ds_write_b128
    }
}

template <bool ATOMIC>
__global__ __launch_bounds__(THREADS, 8) void das_kernel(
    const float* __restrict__ rf, const float* __restrict__ g,
    const float* __restrict__ pr, const float* __restrict__ p,
    float* __restrict__ dst)    // ATOMIC ? out : partials in ws
{
    __shared__ alignas(16) _Float16 sbuf[2][SLAB_H];   // 2 x 32 KiB fp16 dbuf

    const int bid   = blockIdx.x;
    const int chunk = bid & (N_CHUNKS - 1);
    const int tile  = (bid >> 3) & (N_TILES - 1);
    const int b     = bid >> 8;
    const int t     = threadIdx.x;
    const int px0   = tile * PX_PER_BLOCK;

    const float c0v = p[b * 4 + 0];
    const float fsv = p[b * 4 + 1];
    const float t0v = p[b * 4 + 2];
    const float scale = fsv / c0v;            // samples per meter
    const float sb0   = scale * t0v;

    float gx[PX_PER_THREAD], gy[PX_PER_THREAD], gzv[PX_PER_THREAD], sbase[PX_PER_THREAD];
#pragma unroll
    for (int j = 0; j < PX_PER_THREAD; ++j) {
        const int m = px0 + j * THREADS + t;
        const float* gp = g + ((size_t)b * NM + m) * 3;
        gx[j]  = gp[0];
        gy[j]  = gp[1];
        gzv[j] = gp[2];
        sbase[j] = sb0 + scale * gzv[j];      // fs*(t0 + d_tx)/c0 hoisted
    }

    float4 acc[PX_PER_THREAD];
#pragma unroll
    for (int j = 0; j < PX_PER_THREAD; ++j) acc[j] = make_float4(0.f, 0.f, 0.f, 0.f);

    const int ch0 = chunk * C_PER_BLOCK;
    const float* slice0 = rf + (size_t)(b * NC + ch0) * NS * NK;

    // Prologue: stage phase 0
    {
        float4 f[4];
        load_slab(slice0, f, t);
        write_slab(f, &sbuf[0][0], t);
    }
    __syncthreads();

    for (int ph = 0; ph < N_PHASES; ++ph) {
        // Issue next slab's global loads NOW; first use (write_slab) is after
        // compute, so the L2 latency hides under the gathers below.
        float4 nf[4];
        const bool more = (ph + 1 < N_PHASES);
        if (more)
            load_slab(slice0 + (size_t)(ph + 1) * SLAB_F4 * 4, nf, t);

        const _Float16* lb = &sbuf[ph & 1][0];
#pragma unroll
        for (int cc = 0; cc < CH_PER_PHASE; ++cc) {
            const int ch = ch0 + ph * CH_PER_PHASE + cc;
            const float* prp = pr + ((size_t)b * NC + ch) * 3;
            const float prx = prp[0], pry = prp[1], prz = prp[2];
            const _Float16* lc = lb + cc * CH_H;

#pragma unroll
            for (int j = 0; j < PX_PER_THREAD; ++j) {
                const float dx = gx[j]  - prx;
                const float dy = gy[j]  - pry;
                const float dz = gzv[j] - prz;
                const float drx = __builtin_amdgcn_sqrtf(fmaf(dx, dx, fmaf(dy, dy, dz * dz)));
                float s = fmaf(scale, drx, sbase[j]);         // frac sample idx
                s = fminf(fmaxf(s, 0.0f), (float)(NS - 1));
                const float fi = fminf(floorf(s), (float)(NS - 2));
                const float w  = s - fi;
                const float wm = 1.0f - w;
                const int i0 = (int)fi;
                // adjacent 8-B fp16 quads: ds_read2_b64 candidates
                const half4 y0 = *(const half4*)(lc + i0 * 4);
                const half4 y1 = *(const half4*)(lc + i0 * 4 + 4);
                acc[j].x = fmaf((float)y0[0], wm, fmaf((float)y1[0], w, acc[j].x));
                acc[j].y = fmaf((float)y0[1], wm, fmaf((float)y1[1], w, acc[j].y));
                acc[j].z = fmaf((float)y0[2], wm, fmaf((float)y1[2], w, acc[j].z));
                acc[j].w = fmaf((float)y0[3], wm, fmaf((float)y1[3], w, acc[j].w));
            }
        }

        // Consume the prefetch: cvt + LDS write into the other buffer. The
        // buffer being written was last READ in phase ph-1, separated from
        // these writes by the barrier at the end of phase ph-1.
        if (more)
            write_slab(nf, &sbuf[(ph + 1) & 1][0], t);
        __syncthreads();
    }

    if (ATOMIC) {
        float* ob = dst + (size_t)b * NM * NK;
#pragma unroll
        for (int j = 0; j < PX_PER_THREAD; ++j) {
            const int m = px0 + j * THREADS + t;
            float* op = ob + (size_t)m * NK;
            atomicAdd(op + 0, acc[j].x);
            atomicAdd(op + 1, acc[j].y);
            atomicAdd(op + 2, acc[j].z);
            atomicAdd(op + 3, acc[j].w);
        }
    } else {
        // partial[chunk][b][m] as float4 — disjoint per block, plain stores
        float4* pw = (float4*)dst + (size_t)(chunk * NBATCH + b) * NM;
#pragma unroll
        for (int j = 0; j < PX_PER_THREAD; ++j) {
            const int m = px0 + j * THREADS + t;
            pw[m] = acc[j];
        }
    }
}

// out[i] = sum over 8 chunk partials; i indexes float4 over [B*NM)
__global__ __launch_bounds__(256) void reduce_kernel(
    const float4* __restrict__ part, float4* __restrict__ out)
{
    const int i = blockIdx.x * 256 + threadIdx.x;
    const size_t stride = (size_t)NBATCH * NM;
    float4 a = part[i];
#pragma unroll
    for (int c = 1; c < N_CHUNKS; ++c) {
        const float4 v = part[c * stride + i];
        a.x += v.x; a.y += v.y; a.z += v.z; a.w += v.w;
    }
    out[i] = a;
}

extern "C" void kernel_launch(void* const* d_in, const int* in_sizes, int n_in,
                              void* d_out, int out_size, void* d_ws, size_t ws_size,
                              hipStream_t stream) {
    (void)in_sizes; (void)n_in;
    const float* rf = (const float*)d_in[0];
    const float* g  = (const float*)d_in[1];
    const float* pr = (const float*)d_in[2];
    const float* p  = (const float*)d_in[3];
    float* out = (float*)d_out;

    if (ws_size >= PART_BYTES) {
        das_kernel<false><<<NBLOCKS, THREADS, 0, stream>>>(rf, g, pr, p, (float*)d_ws);
        reduce_kernel<<<(NBATCH * NM) / 256, 256, 0, stream>>>((const float4*)d_ws,
                                                               (float4*)out);
    } else {
        hipMemsetAsync(d_out, 0, (size_t)out_size * sizeof(float), stream);
        das_kernel<true><<<NBLOCKS, THREADS, 0, stream>>>(rf, g, pr, p, out);
    }
}

// Round 7
// 92.848 us; speedup vs baseline: 2.9327x; 2.9327x over previous
//
#include <hip/hip_runtime.h>

// DAS beamforming: out[b,z,x,k] = sum_c lerp(rf[b,c], delay(b,c,z,x))[k]
// Round 7: fp16-in-LDS redone with REGISTER DISCIPLINE. R6's 215 us regression
// was scratch spill (FETCH 200 MB / WRITE 397 MB of unasked traffic): holding
// a 16-VGPR prefetch across a 2-channel unrolled gather body blew the 64-VGPR
// cap of __launch_bounds__(1024,8). Fix:
//  - 1 channel per phase (16 KiB fp16 slab), stage = load 2x float4 (fully
//    coalesced), cvt, 2x ds_write_b64, consumed IMMEDIATELY at phase top --
//    nothing live across the gather loop. Latency covered by 32 waves/CU.
//  - gathers 16 B/pair fp16: LDS traffic and bank-conflict cycles halve vs R5.
//  - LDS 2 x 16 KiB dbuf = 32 KiB/block, 2 blocks/CU, 16 barriers (same as R5).
//  - epilogue: disjoint partial stores to ws + reduce (R4: contended atomics
//    ping-pong across XCDs; R3: never READ pre-poisoned ws-resident data --
//    partials are written+read within one replay, so they're L2-warm).

#define NBATCH 2
#define NC 128
#define NS 2048
#define NK 4
#define NM 65536                              // Nz*Nx pixels per batch

#define THREADS 1024
#define PX_PER_THREAD 2
#define PX_PER_BLOCK (THREADS * PX_PER_THREAD)   // 2048
#define C_PER_BLOCK 16
#define N_CHUNKS (NC / C_PER_BLOCK)           // 8
#define N_TILES (NM / PX_PER_BLOCK)           // 32
#define NBLOCKS (NBATCH * N_TILES * N_CHUNKS) // 512 = 2 blocks/CU, 32 waves/CU

#define CH_F (NS * NK)                        // 8192 floats = 32 KiB fp32/channel
#define CH_H (NS * NK)                        // 8192 halves = 16 KiB fp16/channel

#define PART_BYTES ((size_t)N_CHUNKS * NBATCH * NM * NK * 4)  // 16.8 MB

typedef __attribute__((ext_vector_type(4))) _Float16 half4;

// Load one channel slice (8192 floats) with 2 fully-coalesced float4 loads per
// thread, convert to fp16, write as 2x 8-B LDS stores. Short live range: the
// 8 staged VGPRs die inside this function.
__device__ __forceinline__ void stage_cvt(const float* slice, _Float16* buf, int t) {
    const float4* src = (const float4*)slice;
    const float4 a = src[t];              // floats [4t, 4t+4)
    const float4 b = src[t + THREADS];    // floats [4096+4t, ...)
    half4 ha, hb;
    ha[0] = (_Float16)a.x; ha[1] = (_Float16)a.y;
    ha[2] = (_Float16)a.z; ha[3] = (_Float16)a.w;
    hb[0] = (_Float16)b.x; hb[1] = (_Float16)b.y;
    hb[2] = (_Float16)b.z; hb[3] = (_Float16)b.w;
    *(half4*)(buf + 4 * t) = ha;
    *(half4*)(buf + 4 * (t + THREADS)) = hb;
}

template <bool ATOMIC>
__global__ __launch_bounds__(THREADS, 8) void das_kernel(
    const float* __restrict__ rf, const float* __restrict__ g,
    const float* __restrict__ pr, const float* __restrict__ p,
    float* __restrict__ dst)    // ATOMIC ? out : partials in ws
{
    __shared__ alignas(16) _Float16 sbuf[2][CH_H];   // 2 x 16 KiB fp16 dbuf

    const int bid   = blockIdx.x;
    const int chunk = bid & (N_CHUNKS - 1);
    const int tile  = (bid >> 3) & (N_TILES - 1);
    const int b     = bid >> 8;
    const int t     = threadIdx.x;
    const int px0   = tile * PX_PER_BLOCK;

    const float c0v = p[b * 4 + 0];
    const float fsv = p[b * 4 + 1];
    const float t0v = p[b * 4 + 2];
    const float scale = fsv / c0v;            // samples per meter
    const float sb0   = scale * t0v;

    float gx[PX_PER_THREAD], gy[PX_PER_THREAD], gzv[PX_PER_THREAD], sbase[PX_PER_THREAD];
#pragma unroll
    for (int j = 0; j < PX_PER_THREAD; ++j) {
        const int m = px0 + j * THREADS + t;
        const float* gp = g + ((size_t)b * NM + m) * 3;
        gx[j]  = gp[0];
        gy[j]  = gp[1];
        gzv[j] = gp[2];
        sbase[j] = sb0 + scale * gzv[j];      // fs*(t0 + d_tx)/c0 hoisted
    }

    float4 acc[PX_PER_THREAD];
#pragma unroll
    for (int j = 0; j < PX_PER_THREAD; ++j) acc[j] = make_float4(0.f, 0.f, 0.f, 0.f);

    const int ch0 = chunk * C_PER_BLOCK;
    const float* slice0 = rf + (size_t)(b * NC + ch0) * CH_F;

    // Prologue: stage channel 0
    stage_cvt(slice0, &sbuf[0][0], t);
    __syncthreads();

    for (int ph = 0; ph < C_PER_BLOCK; ++ph) {
        // Stage channel ph+1 into the other buffer NOW (immediately consumed,
        // no registers held across the gather loop). Races resolved by the
        // barrier at the end of the previous phase. This wave's load latency
        // is hidden by the 31 other resident waves on this CU.
        if (ph + 1 < C_PER_BLOCK)
            stage_cvt(slice0 + (size_t)(ph + 1) * CH_F, &sbuf[(ph + 1) & 1][0], t);

        const _Float16* lc = &sbuf[ph & 1][0];
        const float* prp = pr + ((size_t)(b * NC + ch0 + ph)) * 3;
        const float prx = prp[0], pry = prp[1], prz = prp[2];

#pragma unroll
        for (int j = 0; j < PX_PER_THREAD; ++j) {
            const float dx = gx[j]  - prx;
            const float dy = gy[j]  - pry;
            const float dz = gzv[j] - prz;
            const float drx = __builtin_amdgcn_sqrtf(fmaf(dx, dx, fmaf(dy, dy, dz * dz)));
            float s = fmaf(scale, drx, sbase[j]);         // frac sample idx
            s = fminf(fmaxf(s, 0.0f), (float)(NS - 1));
            const float fi = fminf(floorf(s), (float)(NS - 2));
            const float w  = s - fi;
            const float wm = 1.0f - w;
            const int i0 = (int)fi;
            // adjacent 8-B fp16 quads: ds_read2_b64 candidate
            const half4 y0 = *(const half4*)(lc + i0 * 4);
            const half4 y1 = *(const half4*)(lc + i0 * 4 + 4);
            acc[j].x = fmaf((float)y0[0], wm, fmaf((float)y1[0], w, acc[j].x));
            acc[j].y = fmaf((float)y0[1], wm, fmaf((float)y1[1], w, acc[j].y));
            acc[j].z = fmaf((float)y0[2], wm, fmaf((float)y1[2], w, acc[j].z));
            acc[j].w = fmaf((float)y0[3], wm, fmaf((float)y1[3], w, acc[j].w));
        }
        __syncthreads();
    }

    if (ATOMIC) {
        float* ob = dst + (size_t)b * NM * NK;
#pragma unroll
        for (int j = 0; j < PX_PER_THREAD; ++j) {
            const int m = px0 + j * THREADS + t;
            float* op = ob + (size_t)m * NK;
            atomicAdd(op + 0, acc[j].x);
            atomicAdd(op + 1, acc[j].y);
            atomicAdd(op + 2, acc[j].z);
            atomicAdd(op + 3, acc[j].w);
        }
    } else {
        // partial[chunk][b][m] as float4 — disjoint per block, plain stores
        float4* pw = (float4*)dst + (size_t)(chunk * NBATCH + b) * NM;
#pragma unroll
        for (int j = 0; j < PX_PER_THREAD; ++j) {
            const int m = px0 + j * THREADS + t;
            pw[m] = acc[j];
        }
    }
}

// out[i] = sum over 8 chunk partials; i indexes float4 over [B*NM)
__global__ __launch_bounds__(256) void reduce_kernel(
    const float4* __restrict__ part, float4* __restrict__ out)
{
    const int i = blockIdx.x * 256 + threadIdx.x;
    const size_t stride = (size_t)NBATCH * NM;
    float4 a = part[i];
#pragma unroll
    for (int c = 1; c < N_CHUNKS; ++c) {
        const float4 v = part[c * stride + i];
        a.x += v.x; a.y += v.y; a.z += v.z; a.w += v.w;
    }
    out[i] = a;
}

extern "C" void kernel_launch(void* const* d_in, const int* in_sizes, int n_in,
                              void* d_out, int out_size, void* d_ws, size_t ws_size,
                              hipStream_t stream) {
    (void)in_sizes; (void)n_in;
    const float* rf = (const float*)d_in[0];
    const float* g  = (const float*)d_in[1];
    const float* pr = (const float*)d_in[2];
    const float* p  = (const float*)d_in[3];
    float* out = (float*)d_out;

    if (ws_size >= PART_BYTES) {
        das_kernel<false><<<NBLOCKS, THREADS, 0, stream>>>(rf, g, pr, p, (float*)d_ws);
        reduce_kernel<<<(NBATCH * NM) / 256, 256, 0, stream>>>((const float4*)d_ws,
                                                               (float4*)out);
    } else {
        hipMemsetAsync(d_out, 0, (size_t)out_size * sizeof(float), stream);
        das_kernel<true><<<NBLOCKS, THREADS, 0, stream>>>(rf, g, pr, p, out);
    }
}